// Round 3
// baseline (4149.053 us; speedup 1.0000x reference)
//
#include <hip/hip_runtime.h>
#include <hip/hip_bf16.h>

typedef __bf16  bf16x8  __attribute__((ext_vector_type(8)));
typedef short   short8_t __attribute__((ext_vector_type(8)));
typedef float   float4_t __attribute__((ext_vector_type(4)));

#define MFMA(a, b, c) __builtin_amdgcn_mfma_f32_16x16x32_bf16((a), (b), (c), 0, 0, 0)

#define LOG2E      1.4426950408889634f
#define TWO_LOG2E  2.8853900817779268f

__device__ __forceinline__ unsigned short f2bf(float f) {
  unsigned u = __builtin_bit_cast(unsigned, f);
  unsigned r = ((u >> 16) & 1u) + 0x7FFFu;   // round-to-nearest-even
  return (unsigned short)((u + r) >> 16);
}
// x pre-scaled by LOG2E
__device__ __forceinline__ float sig2(float x) {
  return __builtin_amdgcn_rcpf(1.f + __builtin_amdgcn_exp2f(-x));
}
// x pre-scaled by 2*LOG2E
__device__ __forceinline__ float tanh2s(float x) {
  return 1.f - 2.f * __builtin_amdgcn_rcpf(1.f + __builtin_amdgcn_exp2f(x));
}

// 256 blocks x 512 threads (8 waves), 32 batch rows/block. Wave w owns hidden
// units [16w,16w+16). Per step, 4 barriers:
//   A:  C0x (x A-frags in regs) + C0h MFMAs (reads h0f)        | b_warA
//       act0 + h0f write (h0(t))                               | b1 (publish)
//   B:  C1 MFMAs (reads h0f(t), h1f(t-1))                      | b_warB
//       act1 + h1f write (h1(t))                               | b2 (publish)
//   C:  proj MFMAs (ALL waves, redundant, read h1f(t)+woutF);
//       x(t+1) integrated in regs (bitwise-identical per wave);
//       transpose via xscr (identical-value benign race, same-wave readback);
//       trajectory stores (w<4) -> drain hidden under next A's MFMAs.
__global__ __launch_bounds__(512, 2) void lstm_roll(
    const float* __restrict__ x0,  const float* __restrict__ W0,
    const float* __restrict__ b0v, const float* __restrict__ W1,
    const float* __restrict__ b1v, const float* __restrict__ Wout,
    const float* __restrict__ bout, const float* __restrict__ dts,
    const int* __restrict__ nsp,   float* __restrict__ out)
{
  __shared__ __align__(16) unsigned short w0h[8 * 4 * 4 * 512];  // 128 KiB W0 h-part B-frags [w][g][kt]
  __shared__ __align__(16) unsigned short woutF[2 * 4 * 512];    //   8 KiB Wout B-frags [n][kt] (dts*DT folded)
  __shared__ __align__(16) unsigned short h0f[4 * 2 * 512];      //   8 KiB h0 A-frags [kt][m]
  __shared__ __align__(16) unsigned short h1f[4 * 2 * 512];      //   8 KiB h1 A-frags [kt][m]
  __shared__ __align__(16) unsigned short xscr[2 * 512];         //   2 KiB x A-frag scratch

  const int tid = threadIdx.x;
  const int w   = tid >> 6;
  const int l   = tid & 63;
  const int lm  = l & 15;
  const int lh  = l >> 4;
  const int T   = nsp[0];
  const long rowStride = (long)(T + 1) * 32;
  const long bbase = (long)blockIdx.x * 32;

  // ---------------- weight gather / packing (once) ----------------
  bf16x8 w0x[4];       // W0 x-part B-frags (K=32)
  bf16x8 w1f[4][8];    // W1 B-frags (K=256; kt 0..3 h0-part, 4..7 h1-part)
  #pragma unroll
  for (int g = 0; g < 4; ++g) {
    const float sc = (g == 2) ? TWO_LOG2E : LOG2E;
    const int col = g * 128 + w * 16 + lm;
    {
      short8_t t8;
      #pragma unroll
      for (int e = 0; e < 8; ++e) t8[e] = (short)f2bf(sc * W0[(lh * 8 + e) * 512 + col]);
      w0x[g] = __builtin_bit_cast(bf16x8, t8);
    }
    #pragma unroll
    for (int kt = 0; kt < 8; ++kt) {
      short8_t t8;
      #pragma unroll
      for (int e = 0; e < 8; ++e) t8[e] = (short)f2bf(sc * W1[(kt * 32 + lh * 8 + e) * 512 + col]);
      w1f[g][kt] = __builtin_bit_cast(bf16x8, t8);
    }
    #pragma unroll
    for (int kt = 0; kt < 4; ++kt) {
      const int base = (((w * 4 + g) * 4) + kt) * 512 + l * 8;
      #pragma unroll
      for (int e = 0; e < 8; ++e)
        w0h[base + e] = f2bf(sc * W0[(32 + kt * 32 + lh * 8 + e) * 512 + col]);
    }
  }
  { // Wout B-frags with dts*DT folded in; 8 frags, one per wave
    const int n = w & 1, kt = w >> 1;
    if (kt < 4) {
      const float csc = dts[n * 16 + lm] * 0.01f;
      const int base = (n * 4 + kt) * 512 + l * 8;
      #pragma unroll
      for (int e = 0; e < 8; ++e)
        woutF[base + e] = f2bf(csc * Wout[(kt * 32 + lh * 8 + e) * 32 + (n * 16 + lm)]);
    }
  }
  float b0r[4], b1r[4];
  #pragma unroll
  for (int g = 0; g < 4; ++g) {
    const float sc = (g == 2) ? TWO_LOG2E : LOG2E;
    b0r[g] = sc * b0v[g * 128 + w * 16 + lm];
    b1r[g] = sc * b1v[g * 128 + w * 16 + lm];
  }
  float boutr2[2];
  #pragma unroll
  for (int n = 0; n < 2; ++n)
    boutr2[n] = bout[n * 16 + lm] * dts[n * 16 + lm] * 0.01f;

  for (int i = tid; i < 4 * 2 * 512; i += 512) { h0f[i] = 0; h1f[i] = 0; }

  // x state in C-layout regs (ALL waves, redundant & bitwise identical):
  // xC[m][n][r] = x[16m + 4*lh + r][16n + lm]
  float4_t xC[2][2];
  #pragma unroll
  for (int m = 0; m < 2; ++m)
    #pragma unroll
    for (int n = 0; n < 2; ++n)
      #pragma unroll
      for (int r = 0; r < 4; ++r)
        xC[m][n][r] = x0[(bbase + 16 * m + 4 * lh + r) * 32 + 16 * n + lm];

  // store mapping (w<4 stores quadrant (m_c, n_c))
  const int m_c = w & 1, n_c = (w >> 1) & 1;
  const long obase0 = (bbase + m_c * 16 + lh * 4) * rowStride + (n_c * 16 + lm);
  if (w < 4) {
    const float4_t xq = m_c ? (n_c ? xC[1][1] : xC[1][0]) : (n_c ? xC[0][1] : xC[0][0]);
    #pragma unroll
    for (int r = 0; r < 4; ++r) out[obase0 + r * rowStride] = xq[r];   // t = 0
  }

  // transpose xC -> xscr (A-frag layout) -> xA regs.  idx(m,n,r) =
  // m*512 + 128*(2n + (lm>>3)) + (4*lh + r)*8 + (lm&7)
  const int xsb = 128 * (lm >> 3) + (4 * lh) * 8 + (lm & 7);
  bf16x8 xA[2];
  #pragma unroll
  for (int m = 0; m < 2; ++m)
    #pragma unroll
    for (int n = 0; n < 2; ++n)
      #pragma unroll
      for (int r = 0; r < 4; ++r)
        xscr[m * 512 + n * 256 + xsb + r * 8] = f2bf(xC[m][n][r]);
  xA[0] = *(const bf16x8*)&xscr[l * 8];
  xA[1] = *(const bf16x8*)&xscr[512 + l * 8];

  // h-write scatter base (fragment layout; same for h0f/h1f)
  const int hwb = ((w >> 1) * 2) * 512 +
                  (lh * 4 + 16 * (2 * (w & 1) + ((lm >> 3) & 1))) * 8 + (lm & 7);

  float4_t c0[2], c1[2];
  #pragma unroll
  for (int m = 0; m < 2; ++m) {
    c0[m] = (float4_t){0.f, 0.f, 0.f, 0.f};
    c1[m] = (float4_t){0.f, 0.f, 0.f, 0.f};
  }

  __syncthreads();   // publish h0f/h1f zeros + woutF

  #pragma unroll 1
  for (int t = 0; t < T; ++t) {
    // ============ Phase A: C0x (regs) + C0h (LDS) ============
    float4_t acc[2][4];
    #pragma unroll
    for (int g = 0; g < 4; ++g) {
      acc[0][g] = (float4_t){b0r[g], b0r[g], b0r[g], b0r[g]};
      acc[1][g] = (float4_t){b0r[g], b0r[g], b0r[g], b0r[g]};
    }
    #pragma unroll
    for (int g = 0; g < 4; ++g) {
      acc[0][g] = MFMA(xA[0], w0x[g], acc[0][g]);
      acc[1][g] = MFMA(xA[1], w0x[g], acc[1][g]);
    }
    #pragma unroll
    for (int kt = 0; kt < 4; ++kt) {
      const bf16x8 a0 = *(const bf16x8*)&h0f[(kt * 2 + 0) * 512 + l * 8];
      const bf16x8 a1 = *(const bf16x8*)&h0f[(kt * 2 + 1) * 512 + l * 8];
      #pragma unroll
      for (int g = 0; g < 4; ++g) {
        const bf16x8 bw = *(const bf16x8*)&w0h[(((w * 4 + g) * 4) + kt) * 512 + l * 8];
        acc[0][g] = MFMA(a0, bw, acc[0][g]);
        acc[1][g] = MFMA(a1, bw, acc[1][g]);
      }
    }
    __syncthreads();   // b_warA: all h0f reads done (also drains phase-C stores)
    #pragma unroll
    for (int m = 0; m < 2; ++m)
      #pragma unroll
      for (int r = 0; r < 4; ++r) {
        const float iv = sig2(acc[m][0][r]);
        const float fv = sig2(acc[m][1][r]);
        const float gv = tanh2s(acc[m][2][r]);
        const float ov = sig2(acc[m][3][r]);
        const float cc = fv * c0[m][r] + iv * gv;
        c0[m][r] = cc;
        h0f[hwb + m * 512 + r * 8] = f2bf(ov * tanh2s(cc * TWO_LOG2E));
      }
    __syncthreads();   // b1: h0f(t) published

    // ============ Phase B: C1 MFMAs ============
    float4_t acc1[2][4];
    #pragma unroll
    for (int g = 0; g < 4; ++g) {
      acc1[0][g] = (float4_t){b1r[g], b1r[g], b1r[g], b1r[g]};
      acc1[1][g] = (float4_t){b1r[g], b1r[g], b1r[g], b1r[g]};
    }
    #pragma unroll
    for (int kt = 0; kt < 4; ++kt) {
      const bf16x8 a0 = *(const bf16x8*)&h0f[(kt * 2 + 0) * 512 + l * 8];
      const bf16x8 a1 = *(const bf16x8*)&h0f[(kt * 2 + 1) * 512 + l * 8];
      #pragma unroll
      for (int g = 0; g < 4; ++g) {
        acc1[0][g] = MFMA(a0, w1f[g][kt], acc1[0][g]);
        acc1[1][g] = MFMA(a1, w1f[g][kt], acc1[1][g]);
      }
    }
    #pragma unroll
    for (int kt = 0; kt < 4; ++kt) {
      const bf16x8 a0 = *(const bf16x8*)&h1f[(kt * 2 + 0) * 512 + l * 8];
      const bf16x8 a1 = *(const bf16x8*)&h1f[(kt * 2 + 1) * 512 + l * 8];
      #pragma unroll
      for (int g = 0; g < 4; ++g) {
        acc1[0][g] = MFMA(a0, w1f[g][kt + 4], acc1[0][g]);
        acc1[1][g] = MFMA(a1, w1f[g][kt + 4], acc1[1][g]);
      }
    }
    __syncthreads();   // b_warB: all h1f(t-1) reads done
    #pragma unroll
    for (int m = 0; m < 2; ++m)
      #pragma unroll
      for (int r = 0; r < 4; ++r) {
        const float iv = sig2(acc1[m][0][r]);
        const float fv = sig2(acc1[m][1][r]);
        const float gv = tanh2s(acc1[m][2][r]);
        const float ov = sig2(acc1[m][3][r]);
        const float cc = fv * c1[m][r] + iv * gv;
        c1[m][r] = cc;
        h1f[hwb + m * 512 + r * 8] = f2bf(ov * tanh2s(cc * TWO_LOG2E));
      }
    __syncthreads();   // b2: h1f(t) published

    // ============ Phase C: redundant proj in ALL waves ============
    float4_t accP[2][2];
    #pragma unroll
    for (int m = 0; m < 2; ++m)
      #pragma unroll
      for (int n = 0; n < 2; ++n)
        accP[m][n] = (float4_t){boutr2[n], boutr2[n], boutr2[n], boutr2[n]};
    #pragma unroll
    for (int kt = 0; kt < 4; ++kt) {
      const bf16x8 a0 = *(const bf16x8*)&h1f[(kt * 2 + 0) * 512 + l * 8];
      const bf16x8 a1 = *(const bf16x8*)&h1f[(kt * 2 + 1) * 512 + l * 8];
      #pragma unroll
      for (int n = 0; n < 2; ++n) {
        const bf16x8 bw = *(const bf16x8*)&woutF[(n * 4 + kt) * 512 + l * 8];
        accP[0][n] = MFMA(a0, bw, accP[0][n]);
        accP[1][n] = MFMA(a1, bw, accP[1][n]);
      }
    }
    #pragma unroll
    for (int m = 0; m < 2; ++m)
      #pragma unroll
      for (int n = 0; n < 2; ++n)
        #pragma unroll
        for (int r = 0; r < 4; ++r)
          xC[m][n][r] += accP[m][n][r];
    // transpose to A-frags via xscr (identical values from all waves)
    #pragma unroll
    for (int m = 0; m < 2; ++m)
      #pragma unroll
      for (int n = 0; n < 2; ++n)
        #pragma unroll
        for (int r = 0; r < 4; ++r)
          xscr[m * 512 + n * 256 + xsb + r * 8] = f2bf(xC[m][n][r]);
    xA[0] = *(const bf16x8*)&xscr[l * 8];
    xA[1] = *(const bf16x8*)&xscr[512 + l * 8];
    // trajectory store x(t+1); drains at next b_warA under phase-A MFMAs
    if (w < 4) {
      const float4_t xq = m_c ? (n_c ? xC[1][1] : xC[1][0]) : (n_c ? xC[0][1] : xC[0][0]);
      const long ob = obase0 + (long)(t + 1) * 32;
      #pragma unroll
      for (int r = 0; r < 4; ++r) out[ob + r * rowStride] = xq[r];
    }
  }
}

extern "C" void kernel_launch(void* const* d_in, const int* in_sizes, int n_in,
                              void* d_out, int out_size, void* d_ws, size_t ws_size,
                              hipStream_t stream) {
  (void)n_in; (void)out_size; (void)d_ws; (void)ws_size;
  const float* x0   = (const float*)d_in[0];
  const float* W0   = (const float*)d_in[1];
  const float* b0   = (const float*)d_in[2];
  const float* W1   = (const float*)d_in[3];
  const float* b1   = (const float*)d_in[4];
  const float* Wout = (const float*)d_in[5];
  const float* bout = (const float*)d_in[6];
  const float* dts  = (const float*)d_in[7];
  const int*   nsp  = (const int*)d_in[8];
  float* out = (float*)d_out;

  const int B    = in_sizes[0] / 32;   // 8192
  const int grid = B / 32;             // 256 blocks, 32 batch rows each
  lstm_roll<<<dim3(grid), dim3(512), 0, stream>>>(x0, W0, b0, W1, b1, Wout, bout, dts, nsp, out);
}

// Round 4
// 2474.888 us; speedup vs baseline: 1.6765x; 1.6765x over previous
//
#include <hip/hip_runtime.h>
#include <hip/hip_bf16.h>

typedef __bf16  bf16x8  __attribute__((ext_vector_type(8)));
typedef short   short8_t __attribute__((ext_vector_type(8)));
typedef float   float4_t __attribute__((ext_vector_type(4)));

#define MFMA(a, b, c) __builtin_amdgcn_mfma_f32_16x16x32_bf16((a), (b), (c), 0, 0, 0)

#define LOG2E      1.4426950408889634f
#define TWO_LOG2E  2.8853900817779268f

__device__ __forceinline__ unsigned short f2bf(float f) {
  unsigned u = __builtin_bit_cast(unsigned, f);
  unsigned r = ((u >> 16) & 1u) + 0x7FFFu;   // round-to-nearest-even
  return (unsigned short)((u + r) >> 16);
}
// x pre-scaled by LOG2E
__device__ __forceinline__ float sig2(float x) {
  return __builtin_amdgcn_rcpf(1.f + __builtin_amdgcn_exp2f(-x));
}
// x pre-scaled by 2*LOG2E
__device__ __forceinline__ float tanh2s(float x) {
  return 1.f - 2.f * __builtin_amdgcn_rcpf(1.f + __builtin_amdgcn_exp2f(x));
}

// 256 blocks x 512 threads (8 waves), 32 batch rows/block. Wave w owns hidden
// units [16w,16w+16). Per step, 4 barriers:
//   R1': cell0 h-part MFMA (32, reads h0f(t-1)) all waves
//        + proj (w<4, t>0: reads h1f(t-1) -> x(t); writes xf frags)
//   b1'  (WAR h0f reads done; xf(t) published; proj's h1f reads done)
//   R2': x-part MFMA (8, reads xf) + act0 m-interleaved + h0f(t) writes
//   b2'  (h0f(t) published)
//   R3': x(t) stores (drain at b3' behind 64 MFMA) + cell1 MFMA (reads
//        h0f(t), h1f(t-1)) + act1 m-interleaved (h1n in regs)
//   b3'  (WAR h1f(t-1) reads done)
//        h1f(t) writes
//   b4'  (h1f(t) published)
__global__ __launch_bounds__(512, 2) void lstm_roll(
    const float* __restrict__ x0,  const float* __restrict__ W0,
    const float* __restrict__ b0v, const float* __restrict__ W1,
    const float* __restrict__ b1v, const float* __restrict__ Wout,
    const float* __restrict__ bout, const float* __restrict__ dts,
    const int* __restrict__ nsp,   float* __restrict__ out)
{
  __shared__ __align__(16) unsigned short w0h[8 * 4 * 4 * 512];  // 128 KiB W0 h-part B-frags [w][g][kt]
  __shared__ __align__(16) unsigned short woutF[2 * 4 * 512];    //   8 KiB Wout B-frags [n][kt] (dts*DT folded)
  __shared__ __align__(16) unsigned short h0f[4 * 2 * 512];      //   8 KiB h0 A-frags [kt][m]
  __shared__ __align__(16) unsigned short h1f[4 * 2 * 512];      //   8 KiB h1 A-frags [kt][m]
  __shared__ __align__(16) unsigned short xf[2 * 512];           //   2 KiB x A-frags [m]

  const int tid = threadIdx.x;
  const int w   = tid >> 6;
  const int l   = tid & 63;
  const int lm  = l & 15;
  const int lh  = l >> 4;
  const int T   = nsp[0];
  const long rowStride = (long)(T + 1) * 32;
  const long bbase = (long)blockIdx.x * 32;

  // ---------------- weight gather / packing (once) ----------------
  bf16x8 w0x[4];       // W0 x-part B-frags (K=32)
  bf16x8 w1f[4][8];    // W1 B-frags (K=256; kt 0..3 h0-part, 4..7 h1-part)
  #pragma unroll
  for (int g = 0; g < 4; ++g) {
    const float sc = (g == 2) ? TWO_LOG2E : LOG2E;
    const int col = g * 128 + w * 16 + lm;
    {
      short8_t t8;
      #pragma unroll
      for (int e = 0; e < 8; ++e) t8[e] = (short)f2bf(sc * W0[(lh * 8 + e) * 512 + col]);
      w0x[g] = __builtin_bit_cast(bf16x8, t8);
    }
    #pragma unroll
    for (int kt = 0; kt < 8; ++kt) {
      short8_t t8;
      #pragma unroll
      for (int e = 0; e < 8; ++e) t8[e] = (short)f2bf(sc * W1[(kt * 32 + lh * 8 + e) * 512 + col]);
      w1f[g][kt] = __builtin_bit_cast(bf16x8, t8);
    }
    #pragma unroll
    for (int kt = 0; kt < 4; ++kt) {
      const int base = (((w * 4 + g) * 4) + kt) * 512 + l * 8;
      #pragma unroll
      for (int e = 0; e < 8; ++e)
        w0h[base + e] = f2bf(sc * W0[(32 + kt * 32 + lh * 8 + e) * 512 + col]);
    }
  }
  { // Wout B-frags with dts*DT folded in; 8 frags, one per wave
    const int n = w & 1, kt = w >> 1;
    if (kt < 4) {
      const float csc = dts[n * 16 + lm] * 0.01f;
      const int base = (n * 4 + kt) * 512 + l * 8;
      #pragma unroll
      for (int e = 0; e < 8; ++e)
        woutF[base + e] = f2bf(csc * Wout[(kt * 32 + lh * 8 + e) * 32 + (n * 16 + lm)]);
    }
  }
  float b0r[4], b1r[4];
  #pragma unroll
  for (int g = 0; g < 4; ++g) {
    const float sc = (g == 2) ? TWO_LOG2E : LOG2E;
    b0r[g] = sc * b0v[g * 128 + w * 16 + lm];
    b1r[g] = sc * b1v[g * 128 + w * 16 + lm];
  }

  // proj mapping: waves 0..3 own (m_c, n_c) output quadrant
  const int m_c = w & 1, n_c = (w >> 1) & 1;
  float boutr = 0.f, xr[4] = {0.f, 0.f, 0.f, 0.f};
  long obase0 = 0;
  int  xfbase = 0;
  if (w < 4) {
    boutr = bout[n_c * 16 + lm] * dts[n_c * 16 + lm] * 0.01f;
    const int kin = n_c * 16 + lm;
    xfbase = m_c * 512 + (lh * 4 + 16 * (kin >> 3)) * 8 + (kin & 7);
    obase0 = (bbase + m_c * 16 + lh * 4) * rowStride + (n_c * 16 + lm);
    #pragma unroll
    for (int r = 0; r < 4; ++r) {
      xr[r] = x0[(bbase + m_c * 16 + lh * 4 + r) * 32 + n_c * 16 + lm];
      out[obase0 + r * rowStride] = xr[r];               // trajectory t = 0
      xf[xfbase + r * 8] = f2bf(xr[r]);
    }
  }
  for (int i = tid; i < 4 * 2 * 512; i += 512) { h0f[i] = 0; h1f[i] = 0; }

  // h-write scatter base (fragment layout; same for h0f/h1f)
  const int hwb = ((w >> 1) * 2) * 512 +
                  (lh * 4 + 16 * (2 * (w & 1) + ((lm >> 3) & 1))) * 8 + (lm & 7);

  float4_t c0[2], c1[2];
  #pragma unroll
  for (int m = 0; m < 2; ++m) {
    c0[m] = (float4_t){0.f, 0.f, 0.f, 0.f};
    c1[m] = (float4_t){0.f, 0.f, 0.f, 0.f};
  }

  __syncthreads();   // publish xf(0), h0f/h1f zeros, w0h, woutF

  #pragma unroll 1
  for (int t = 0; t < T; ++t) {
    // ============ R1': cell0 h-part + proj(h1(t-1)) ============
    float4_t acc0[2][4];
    #pragma unroll
    for (int g = 0; g < 4; ++g) {
      acc0[0][g] = (float4_t){b0r[g], b0r[g], b0r[g], b0r[g]};
      acc0[1][g] = (float4_t){b0r[g], b0r[g], b0r[g], b0r[g]};
    }
    #pragma unroll
    for (int kt = 0; kt < 4; ++kt) {
      const bf16x8 a0 = *(const bf16x8*)&h0f[(kt * 2 + 0) * 512 + l * 8];
      const bf16x8 a1 = *(const bf16x8*)&h0f[(kt * 2 + 1) * 512 + l * 8];
      #pragma unroll
      for (int g = 0; g < 4; ++g) {
        const bf16x8 bw = *(const bf16x8*)&w0h[(((w * 4 + g) * 4) + kt) * 512 + l * 8];
        acc0[0][g] = MFMA(a0, bw, acc0[0][g]);
        acc0[1][g] = MFMA(a1, bw, acc0[1][g]);
      }
    }
    if (w < 4 && t > 0) {   // proj: x(t) = x(t-1) + h1(t-1) @ WoutF
      float4_t dacc = (float4_t){boutr, boutr, boutr, boutr};
      #pragma unroll
      for (int kt = 0; kt < 4; ++kt) {
        const bf16x8 a  = *(const bf16x8*)&h1f[(kt * 2 + m_c) * 512 + l * 8];
        const bf16x8 bw = *(const bf16x8*)&woutF[(n_c * 4 + kt) * 512 + l * 8];
        dacc = MFMA(a, bw, dacc);
      }
      #pragma unroll
      for (int r = 0; r < 4; ++r) {
        xr[r] += dacc[r];
        xf[xfbase + r * 8] = f2bf(xr[r]);
      }
    }
    __syncthreads();   // b1': h0f/h1f(t-1) reads done; xf(t) published

    // ============ R2': x-part + act0 (m-interleaved) + h0f writes ============
    {
      const bf16x8 ax0 = *(const bf16x8*)&xf[l * 8];
      #pragma unroll
      for (int g = 0; g < 4; ++g) acc0[0][g] = MFMA(ax0, w0x[g], acc0[0][g]);
      const bf16x8 ax1 = *(const bf16x8*)&xf[512 + l * 8];
      // act0 m=0 overlaps m=1 x-part MFMAs
      #pragma unroll
      for (int r = 0; r < 4; ++r) {
        const float iv = sig2(acc0[0][0][r]);
        const float fv = sig2(acc0[0][1][r]);
        const float gv = tanh2s(acc0[0][2][r]);
        const float ov = sig2(acc0[0][3][r]);
        const float cc = fv * c0[0][r] + iv * gv;
        c0[0][r] = cc;
        h0f[hwb + r * 8] = f2bf(ov * tanh2s(cc * TWO_LOG2E));
      }
      #pragma unroll
      for (int g = 0; g < 4; ++g) acc0[1][g] = MFMA(ax1, w0x[g], acc0[1][g]);
      #pragma unroll
      for (int r = 0; r < 4; ++r) {
        const float iv = sig2(acc0[1][0][r]);
        const float fv = sig2(acc0[1][1][r]);
        const float gv = tanh2s(acc0[1][2][r]);
        const float ov = sig2(acc0[1][3][r]);
        const float cc = fv * c0[1][r] + iv * gv;
        c0[1][r] = cc;
        h0f[hwb + 512 + r * 8] = f2bf(ov * tanh2s(cc * TWO_LOG2E));
      }
    }
    __syncthreads();   // b2': h0f(t) published

    // ============ R3': x stores + cell1 + act1 (m-interleaved) ============
    if (w < 4 && t > 0) {   // store x(t); drains at b3' behind 64 MFMAs
      const long ob = obase0 + (long)t * 32;
      #pragma unroll
      for (int r = 0; r < 4; ++r) out[ob + r * rowStride] = xr[r];
    }
    float4_t acc1[2][4];
    #pragma unroll
    for (int g = 0; g < 4; ++g) {
      acc1[0][g] = (float4_t){b1r[g], b1r[g], b1r[g], b1r[g]};
      acc1[1][g] = (float4_t){b1r[g], b1r[g], b1r[g], b1r[g]};
    }
    // m=0 accumulation (h0-part then h1-part)
    #pragma unroll
    for (int kt = 0; kt < 4; ++kt) {
      const bf16x8 a = *(const bf16x8*)&h0f[(kt * 2 + 0) * 512 + l * 8];
      #pragma unroll
      for (int g = 0; g < 4; ++g) acc1[0][g] = MFMA(a, w1f[g][kt], acc1[0][g]);
    }
    #pragma unroll
    for (int kt = 0; kt < 4; ++kt) {
      const bf16x8 a = *(const bf16x8*)&h1f[(kt * 2 + 0) * 512 + l * 8];
      #pragma unroll
      for (int g = 0; g < 4; ++g) acc1[0][g] = MFMA(a, w1f[g][kt + 4], acc1[0][g]);
    }
    // act1 m=0 overlaps m=1 MFMAs
    float h1n[2][4];
    #pragma unroll
    for (int r = 0; r < 4; ++r) {
      const float iv = sig2(acc1[0][0][r]);
      const float fv = sig2(acc1[0][1][r]);
      const float gv = tanh2s(acc1[0][2][r]);
      const float ov = sig2(acc1[0][3][r]);
      const float cc = fv * c1[0][r] + iv * gv;
      c1[0][r] = cc;
      h1n[0][r] = ov * tanh2s(cc * TWO_LOG2E);
    }
    #pragma unroll
    for (int kt = 0; kt < 4; ++kt) {
      const bf16x8 a = *(const bf16x8*)&h0f[(kt * 2 + 1) * 512 + l * 8];
      #pragma unroll
      for (int g = 0; g < 4; ++g) acc1[1][g] = MFMA(a, w1f[g][kt], acc1[1][g]);
    }
    #pragma unroll
    for (int kt = 0; kt < 4; ++kt) {
      const bf16x8 a = *(const bf16x8*)&h1f[(kt * 2 + 1) * 512 + l * 8];
      #pragma unroll
      for (int g = 0; g < 4; ++g) acc1[1][g] = MFMA(a, w1f[g][kt + 4], acc1[1][g]);
    }
    #pragma unroll
    for (int r = 0; r < 4; ++r) {
      const float iv = sig2(acc1[1][0][r]);
      const float fv = sig2(acc1[1][1][r]);
      const float gv = tanh2s(acc1[1][2][r]);
      const float ov = sig2(acc1[1][3][r]);
      const float cc = fv * c1[1][r] + iv * gv;
      c1[1][r] = cc;
      h1n[1][r] = ov * tanh2s(cc * TWO_LOG2E);
    }
    __syncthreads();   // b3': h1f(t-1) reads done (cell1 + next proj safe)
    #pragma unroll
    for (int m = 0; m < 2; ++m)
      #pragma unroll
      for (int r = 0; r < 4; ++r)
        h1f[hwb + m * 512 + r * 8] = f2bf(h1n[m][r]);
    __syncthreads();   // b4': h1f(t) published
  }

  // ============ Epilogue: x(T) from h1(T-1) ============
  if (w < 4) {
    float4_t dacc = (float4_t){boutr, boutr, boutr, boutr};
    #pragma unroll
    for (int kt = 0; kt < 4; ++kt) {
      const bf16x8 a  = *(const bf16x8*)&h1f[(kt * 2 + m_c) * 512 + l * 8];
      const bf16x8 bw = *(const bf16x8*)&woutF[(n_c * 4 + kt) * 512 + l * 8];
      dacc = MFMA(a, bw, dacc);
    }
    const long ob = obase0 + (long)T * 32;
    #pragma unroll
    for (int r = 0; r < 4; ++r) {
      xr[r] += dacc[r];
      out[ob + r * rowStride] = xr[r];
    }
  }
}

extern "C" void kernel_launch(void* const* d_in, const int* in_sizes, int n_in,
                              void* d_out, int out_size, void* d_ws, size_t ws_size,
                              hipStream_t stream) {
  (void)n_in; (void)out_size; (void)d_ws; (void)ws_size;
  const float* x0   = (const float*)d_in[0];
  const float* W0   = (const float*)d_in[1];
  const float* b0   = (const float*)d_in[2];
  const float* W1   = (const float*)d_in[3];
  const float* b1   = (const float*)d_in[4];
  const float* Wout = (const float*)d_in[5];
  const float* bout = (const float*)d_in[6];
  const float* dts  = (const float*)d_in[7];
  const int*   nsp  = (const int*)d_in[8];
  float* out = (float*)d_out;

  const int B    = in_sizes[0] / 32;   // 8192
  const int grid = B / 32;             // 256 blocks, 32 batch rows each
  lstm_roll<<<dim3(grid), dim3(512), 0, stream>>>(x0, W0, b0, W1, b1, Wout, bout, dts, nsp, out);
}